// Round 5
// baseline (101.364 us; speedup 1.0000x reference)
//
#include <hip/hip_runtime.h>
#include <hip/hip_bf16.h>

#define S_LEN 4096
#define DK    64
#define BQ    64
#define BK    64

typedef __bf16 bf16x8 __attribute__((ext_vector_type(8)));
typedef float  f32x4  __attribute__((ext_vector_type(4)));

__device__ __forceinline__ short f2bf(float f) {
    union { __bf16 h; short s; } u; u.h = (__bf16)f; return u.s;
}

// Flash attention, causal, scale=1/64 (folded into Q), pad-mask (s==0 -> -inf).
// 512 blocks x 256 threads, one q-tile per block. Balance trick: co-resident
// blocks (i, i+256) land on the same CU (round-robin dispatch, observed R2);
// qb = (batch<4) ? 63-x : x makes each CU's pair sum to 65 k-tiles, and the
// two blocks are independent streams (phase-offset barriers overlap stalls).
__global__ __launch_bounds__(256, 2) void attn_kernel(
    const float* __restrict__ Q, const float* __restrict__ K,
    const float* __restrict__ V, float* __restrict__ O)
{
    __shared__ __align__(16) short Ks[2][BK * DK];   // [key][dk] bf16, swizzled
    __shared__ __align__(16) short Vts[2][DK * BK];  // [dk][key] bf16, swizzled
    __shared__ __align__(16) short Ps[4][16 * BK];   // per-wave P, swizzled

    const int tid  = threadIdx.x;
    const int wave = tid >> 6;
    const int lane = tid & 63;
    const int lg   = lane >> 4;
    const int lr   = lane & 15;
    const int dk0  = lg * 8;

    const int batch = blockIdx.y;
    const int qb    = (batch < 4) ? (63 - (int)blockIdx.x) : (int)blockIdx.x;
    const int q0    = qb * BQ;
    const size_t bo = (size_t)batch * S_LEN * DK;
    const float* Kb = K + bo;
    const float* Vb = V + bo;

    const int srow = tid >> 4;         // 0..15
    const int scol = (tid & 15) * 4;   // 0..60
    const int vr0  = (tid >> 4) * 4;   // V 4x4 transpose block row base

    float4 kreg[4];
    float  vregf[4][4];

    auto load_tile = [&](int k0) {
        const float* Kt = Kb + (size_t)k0 * DK;
        const float* Vt = Vb + (size_t)k0 * DK;
        #pragma unroll
        for (int i = 0; i < 4; ++i)
            kreg[i] = *reinterpret_cast<const float4*>(Kt + (i * 16 + srow) * DK + scol);
        #pragma unroll
        for (int j = 0; j < 4; ++j) {
            const float4 f = *reinterpret_cast<const float4*>(Vt + (vr0 + j) * DK + scol);
            vregf[j][0] = f.x; vregf[j][1] = f.y; vregf[j][2] = f.z; vregf[j][3] = f.w;
        }
    };

    auto store_tile = [&](int b) {
        short* Kd = &Ks[b][0];
        short* Vd = &Vts[b][0];
        #pragma unroll
        for (int i = 0; i < 4; ++i) {
            const int row = i * 16 + srow;
            short4 sp;
            sp.x = f2bf(kreg[i].x); sp.y = f2bf(kreg[i].y);
            sp.z = f2bf(kreg[i].z); sp.w = f2bf(kreg[i].w);
            *reinterpret_cast<short4*>(&Kd[row * 64 + (scol ^ ((row & 7) << 3))]) = sp;
        }
        #pragma unroll
        for (int j2 = 0; j2 < 4; ++j2) {
            const int d = scol + j2;
            short4 sp;
            sp.x = f2bf(vregf[0][j2]); sp.y = f2bf(vregf[1][j2]);
            sp.z = f2bf(vregf[2][j2]); sp.w = f2bf(vregf[3][j2]);
            *reinterpret_cast<short4*>(&Vd[d * 64 + (vr0 ^ ((d & 7) << 3))]) = sp;
        }
    };

    // Q fragments with 1/64 scale folded in
    bf16x8 qf[2];
    {
        const float* Qr = Q + bo + (size_t)(q0 + 16 * wave + lr) * DK;
        #pragma unroll
        for (int s = 0; s < 2; ++s) {
            const float4 a = *reinterpret_cast<const float4*>(Qr + 32 * s + dk0);
            const float4 b = *reinterpret_cast<const float4*>(Qr + 32 * s + dk0 + 4);
            qf[s][0] = (__bf16)(a.x * 0.015625f); qf[s][1] = (__bf16)(a.y * 0.015625f);
            qf[s][2] = (__bf16)(a.z * 0.015625f); qf[s][3] = (__bf16)(a.w * 0.015625f);
            qf[s][4] = (__bf16)(b.x * 0.015625f); qf[s][5] = (__bf16)(b.y * 0.015625f);
            qf[s][6] = (__bf16)(b.z * 0.015625f); qf[s][7] = (__bf16)(b.w * 0.015625f);
        }
    }

    const float NEG_INF = -__builtin_inff();
    float m_run[4], l_run[4];
    f32x4 oa[4];
    #pragma unroll
    for (int r = 0; r < 4; ++r) { m_run[r] = NEG_INF; l_run[r] = 0.f; }
    #pragma unroll
    for (int u = 0; u < 4; ++u) oa[u] = (f32x4){0.f, 0.f, 0.f, 0.f};

    const int rowq   = q0 + 16 * wave + 4 * lg;
    const int ntiles = qb + 1;

    load_tile(0);
    store_tile(0);
    __syncthreads();

    for (int kt = 0; kt < ntiles; ++kt) {
        const int cur = kt & 1;
        const bool pf = (kt + 1 < ntiles);
        if (pf) load_tile((kt + 1) * BK);   // latency hides under compute

        const short* Kc = &Ks[cur][0];
        const short* Vc = &Vts[cur][0];
        const int k0 = kt * BK;
        const bool diag = (kt == qb);

        // ---- S = Q K^T
        f32x4 sa[4];
        #pragma unroll
        for (int t = 0; t < 4; ++t) {
            sa[t] = (f32x4){0.f, 0.f, 0.f, 0.f};
            const int krow = 16 * t + lr;
            const int swz  = (krow & 7) << 3;
            #pragma unroll
            for (int s = 0; s < 2; ++s) {
                const bf16x8 kf = *reinterpret_cast<const bf16x8*>(&Kc[krow * 64 + ((32 * s + dk0) ^ swz)]);
                sa[t] = __builtin_amdgcn_mfma_f32_16x16x32_bf16(qf[s], kf, sa[t], 0, 0, 0);
            }
        }

        // ---- masks + online softmax (l lane-partial; reduced in epilogue)
        float spv[4][4];
        float mt[4] = {NEG_INF, NEG_INF, NEG_INF, NEG_INF};
        #pragma unroll
        for (int t = 0; t < 4; ++t) {
            const int key = k0 + 16 * t + lr;
            #pragma unroll
            for (int r = 0; r < 4; ++r) {
                float x = sa[t][r];
                x = (x == 0.0f) ? NEG_INF : x;                 // pad mask
                if (diag && key > rowq + r) x = NEG_INF;       // causal (diag tile)
                spv[t][r] = x;
                mt[r] = fmaxf(mt[r], x);
            }
        }
        #pragma unroll
        for (int off = 8; off >= 1; off >>= 1)
            #pragma unroll
            for (int r = 0; r < 4; ++r)
                mt[r] = fmaxf(mt[r], __shfl_xor(mt[r], off));

        float alpha[4];
        bool chg = false;
        #pragma unroll
        for (int r = 0; r < 4; ++r) {
            const float mnew = fmaxf(m_run[r], mt[r]);
            alpha[r] = (m_run[r] == NEG_INF) ? 0.f : __expf(m_run[r] - mnew);
            chg = chg || (mnew != m_run[r]);
            m_run[r] = mnew;
        }
        short pb[4][4];
        float psum[4] = {0.f, 0.f, 0.f, 0.f};
        #pragma unroll
        for (int t = 0; t < 4; ++t)
            #pragma unroll
            for (int r = 0; r < 4; ++r) {
                const float x = spv[t][r];
                const float p = (x == NEG_INF) ? 0.f : __expf(x - m_run[r]);
                psum[r] += p;
                pb[t][r] = f2bf(p);
            }
        if (__all(!chg)) {  // T13: max unchanged -> alpha==1, skip rescale
            #pragma unroll
            for (int r = 0; r < 4; ++r)
                l_run[r] += psum[r];
        } else {
            #pragma unroll
            for (int r = 0; r < 4; ++r)
                l_run[r] = alpha[r] * l_run[r] + psum[r];
            #pragma unroll
            for (int u = 0; u < 4; ++u)
                #pragma unroll
                for (int r = 0; r < 4; ++r)
                    oa[u][r] *= alpha[r];
        }

        // ---- P -> per-wave LDS (wave-local, in-order)
        short* Pw = &Ps[wave][0];
        #pragma unroll
        for (int r = 0; r < 4; ++r) {
            const int prow = 4 * lg + r;
            const int swz  = (prow & 7) << 3;
            #pragma unroll
            for (int t = 0; t < 4; ++t)
                Pw[prow * 64 + ((16 * t + lr) ^ swz)] = pb[t][r];
        }

        // ---- O += P V
        bf16x8 pa[2];
        #pragma unroll
        for (int s = 0; s < 2; ++s)
            pa[s] = *reinterpret_cast<const bf16x8*>(&Pw[lr * 64 + ((32 * s + dk0) ^ ((lr & 7) << 3))]);
        #pragma unroll
        for (int u = 0; u < 4; ++u) {
            const int vrow = 16 * u + lr;
            const int swz  = (vrow & 7) << 3;
            #pragma unroll
            for (int s = 0; s < 2; ++s) {
                const bf16x8 vbf = *reinterpret_cast<const bf16x8*>(&Vc[vrow * 64 + ((32 * s + dk0) ^ swz)]);
                oa[u] = __builtin_amdgcn_mfma_f32_16x16x32_bf16(pa[s], vbf, oa[u], 0, 0, 0);
            }
        }

        if (pf) store_tile(cur ^ 1);  // write other buffer; one barrier orders all
        __syncthreads();
    }

    // ---- epilogue: reduce l across the 16-lane group, then O / l
    #pragma unroll
    for (int off = 8; off >= 1; off >>= 1)
        #pragma unroll
        for (int r = 0; r < 4; ++r)
            l_run[r] += __shfl_xor(l_run[r], off);
    float inv[4];
    #pragma unroll
    for (int r = 0; r < 4; ++r) inv[r] = (l_run[r] > 0.f) ? (1.0f / l_run[r]) : 0.f;
    float* Ob = O + bo + (size_t)(q0 + 16 * wave) * DK;
    #pragma unroll
    for (int u = 0; u < 4; ++u)
        #pragma unroll
        for (int r = 0; r < 4; ++r)
            Ob[(size_t)(4 * lg + r) * DK + 16 * u + lr] = oa[u][r] * inv[r];
}

extern "C" void kernel_launch(void* const* d_in, const int* in_sizes, int n_in,
                              void* d_out, int out_size, void* d_ws, size_t ws_size,
                              hipStream_t stream) {
    (void)in_sizes; (void)n_in; (void)d_ws; (void)ws_size; (void)out_size;
    const float* q = (const float*)d_in[0];
    const float* k = (const float*)d_in[1];
    const float* v = (const float*)d_in[2];
    float* o = (float*)d_out;
    dim3 grid(64, 8);
    dim3 block(256);
    hipLaunchKernelGGL(attn_kernel, grid, block, 0, stream, q, k, v, o);
}

// Round 6
// 84.488 us; speedup vs baseline: 1.1997x; 1.1997x over previous
//
#include <hip/hip_runtime.h>
#include <hip/hip_bf16.h>

#define S_LEN 4096
#define DK    64
#define BQ    64
#define BK    64

typedef __bf16 bf16x8 __attribute__((ext_vector_type(8)));
typedef float  f32x4  __attribute__((ext_vector_type(4)));

__device__ __forceinline__ short f2bf(float f) {
    union { __bf16 h; short s; } u; u.h = (__bf16)f; return u.s;
}
__device__ __forceinline__ float bf2f(short s) {
    union { float f; unsigned u; } u; u.u = ((unsigned)(unsigned short)s) << 16; return u.f;
}

// Flash attention, causal, scale=1/64 (folded into Q), pad-mask (s==0 -> -inf).
// 256 blocks x 512 threads. Block x of batch b handles q-tiles (63-x) and (x):
// constant 65 k-tiles/block, all 8 waves equally loaded the whole run.
// 8 waves = 2 key-split groups x 4 q-subtiles; group g computes k-tile 2p+g.
// Quad-buffered staging (double-buffered PAIRS) -> ONE barrier per pair-iter:
//   load regs(p+1) -> compute buf[p&1] -> store buf[(p+1)&1] -> barrier.
__global__ __launch_bounds__(512, 2) void attn_kernel(
    const float* __restrict__ Q, const float* __restrict__ K,
    const float* __restrict__ V, float* __restrict__ O)
{
    __shared__ __align__(16) short Ks[2][2][BK * DK];   // [pbuf][tile-in-pair][key][dk]
    __shared__ __align__(16) short Vts[2][2][DK * BK];  // [pbuf][tile-in-pair][dk][key]
    __shared__ __align__(16) short Ps[8][16 * BK];      // per-wave P / merge-O buffers
    __shared__ float Ml[4][16][2];                       // merge m,l from group 1

    const int tid  = threadIdx.x;
    const int wave = tid >> 6;
    const int lane = tid & 63;
    const int lg   = lane >> 4;
    const int lr   = lane & 15;
    const int dk0  = lg * 8;
    const int grp  = wave >> 2;   // key-split group 0/1
    const int qsub = wave & 3;    // 16-row q sub-tile

    const int batch = blockIdx.y;
    const size_t bo = (size_t)batch * S_LEN * DK;
    const float* Kb = K + bo;
    const float* Vb = V + bo;

    // staging coords: 512 threads stage a PAIR of 64x64 tiles (K and V^T)
    const int stt  = tid >> 8;         // tile within pair
    const int sidx = tid & 255;
    const int skr  = sidx >> 4;        // 0..15
    const int skc  = (sidx & 15) * 4;  // 0..60

    float4 kreg[4], vreg[4];

    auto load_pair = [&](int kbase) {
        const float* Kt = Kb + (size_t)(kbase + stt * BK) * DK;
        const float* Vt = Vb + (size_t)(kbase + stt * BK) * DK;
        #pragma unroll
        for (int i = 0; i < 4; ++i)
            kreg[i] = *reinterpret_cast<const float4*>(Kt + (i * 16 + skr) * DK + skc);
        #pragma unroll
        for (int j = 0; j < 4; ++j)
            vreg[j] = *reinterpret_cast<const float4*>(Vt + (skr * 4 + j) * DK + skc);
    };
    auto store_pair = [&](int pb) {
        short* Kd = &Ks[pb][stt][0];
        short* Vd = &Vts[pb][stt][0];
        #pragma unroll
        for (int i = 0; i < 4; ++i) {
            const int row = i * 16 + skr;
            short4 sp;
            sp.x = f2bf(kreg[i].x); sp.y = f2bf(kreg[i].y);
            sp.z = f2bf(kreg[i].z); sp.w = f2bf(kreg[i].w);
            *reinterpret_cast<short4*>(&Kd[row * 64 + (skc ^ ((row & 7) << 3))]) = sp;
        }
        const int key0 = skr * 4;  // V^T: 4x4 transpose block
        #pragma unroll
        for (int j2 = 0; j2 < 4; ++j2) {
            const int d = skc + j2;
            short4 sp;
            sp.x = f2bf(reinterpret_cast<const float*>(&vreg[0])[j2]);
            sp.y = f2bf(reinterpret_cast<const float*>(&vreg[1])[j2]);
            sp.z = f2bf(reinterpret_cast<const float*>(&vreg[2])[j2]);
            sp.w = f2bf(reinterpret_cast<const float*>(&vreg[3])[j2]);
            *reinterpret_cast<short4*>(&Vd[d * 64 + (key0 ^ ((d & 7) << 3))]) = sp;
        }
    };

    const float NEG_INF = -__builtin_inff();

    #pragma unroll 1
    for (int qi = 0; qi < 2; ++qi) {
        const int qb = qi ? (int)blockIdx.x : 63 - (int)blockIdx.x;
        const int q0 = qb * BQ;
        const int ntiles = qb + 1;
        const int npairs = (ntiles + 1) >> 1;

        // Q fragments with 1/64 folded in
        bf16x8 qf[2];
        {
            const float* Qr = Q + bo + (size_t)(q0 + 16 * qsub + lr) * DK;
            #pragma unroll
            for (int s = 0; s < 2; ++s) {
                const float4 a = *reinterpret_cast<const float4*>(Qr + 32 * s + dk0);
                const float4 b = *reinterpret_cast<const float4*>(Qr + 32 * s + dk0 + 4);
                qf[s][0] = (__bf16)(a.x * 0.015625f); qf[s][1] = (__bf16)(a.y * 0.015625f);
                qf[s][2] = (__bf16)(a.z * 0.015625f); qf[s][3] = (__bf16)(a.w * 0.015625f);
                qf[s][4] = (__bf16)(b.x * 0.015625f); qf[s][5] = (__bf16)(b.y * 0.015625f);
                qf[s][6] = (__bf16)(b.z * 0.015625f); qf[s][7] = (__bf16)(b.w * 0.015625f);
            }
        }

        float m_run[4], l_run[4];
        f32x4 oa[4];
        #pragma unroll
        for (int r = 0; r < 4; ++r) { m_run[r] = NEG_INF; l_run[r] = 0.f; }
        #pragma unroll
        for (int u = 0; u < 4; ++u) oa[u] = (f32x4){0.f, 0.f, 0.f, 0.f};

        const int rowq = q0 + 16 * qsub + 4 * lg;

        load_pair(0);
        store_pair(0);
        __syncthreads();

        for (int p = 0; p < npairs; ++p) {
            const int kt = 2 * p + grp;
            const bool pf = (p + 1 < npairs);
            if (pf) load_pair((p + 1) * 2 * BK);  // latency hides under compute

            if (kt < ntiles) {
                const short* Kc = &Ks[p & 1][grp][0];
                const short* Vc = &Vts[p & 1][grp][0];
                const int k0 = kt * BK;
                const bool diag = (kt == qb);

                // S = Q K^T
                f32x4 sa[4];
                #pragma unroll
                for (int t = 0; t < 4; ++t) {
                    sa[t] = (f32x4){0.f, 0.f, 0.f, 0.f};
                    const int krow = 16 * t + lr;
                    const int swz  = (krow & 7) << 3;
                    #pragma unroll
                    for (int s = 0; s < 2; ++s) {
                        const bf16x8 kf = *reinterpret_cast<const bf16x8*>(&Kc[krow * 64 + ((32 * s + dk0) ^ swz)]);
                        sa[t] = __builtin_amdgcn_mfma_f32_16x16x32_bf16(qf[s], kf, sa[t], 0, 0, 0);
                    }
                }

                // masks + online softmax (l lane-partial until merge)
                float spv[4][4];
                float mt[4] = {NEG_INF, NEG_INF, NEG_INF, NEG_INF};
                #pragma unroll
                for (int t = 0; t < 4; ++t) {
                    const int key = k0 + 16 * t + lr;
                    #pragma unroll
                    for (int r = 0; r < 4; ++r) {
                        float x = sa[t][r];
                        x = (x == 0.0f) ? NEG_INF : x;             // pad mask
                        if (diag && key > rowq + r) x = NEG_INF;   // causal (diag tile)
                        spv[t][r] = x;
                        mt[r] = fmaxf(mt[r], x);
                    }
                }
                #pragma unroll
                for (int off = 8; off >= 1; off >>= 1)
                    #pragma unroll
                    for (int r = 0; r < 4; ++r)
                        mt[r] = fmaxf(mt[r], __shfl_xor(mt[r], off));

                float alpha[4];
                bool chg = false;
                #pragma unroll
                for (int r = 0; r < 4; ++r) {
                    const float mnew = fmaxf(m_run[r], mt[r]);
                    alpha[r] = (m_run[r] == NEG_INF) ? 0.f : __expf(m_run[r] - mnew);
                    chg = chg || (mnew != m_run[r]);
                    m_run[r] = mnew;
                }
                short pb[4][4];
                float psum[4] = {0.f, 0.f, 0.f, 0.f};
                #pragma unroll
                for (int t = 0; t < 4; ++t)
                    #pragma unroll
                    for (int r = 0; r < 4; ++r) {
                        const float x = spv[t][r];
                        const float pv = (x == NEG_INF) ? 0.f : __expf(x - m_run[r]);
                        psum[r] += pv;
                        pb[t][r] = f2bf(pv);
                    }
                if (__all(!chg)) {  // T13: max unchanged -> alpha==1, skip O rescale
                    #pragma unroll
                    for (int r = 0; r < 4; ++r)
                        l_run[r] += psum[r];
                } else {
                    #pragma unroll
                    for (int r = 0; r < 4; ++r)
                        l_run[r] = alpha[r] * l_run[r] + psum[r];
                    #pragma unroll
                    for (int u = 0; u < 4; ++u)
                        #pragma unroll
                        for (int r = 0; r < 4; ++r)
                            oa[u][r] *= alpha[r];
                }

                // P -> per-wave LDS (wave-local, in-order)
                short* Pw = &Ps[wave][0];
                #pragma unroll
                for (int r = 0; r < 4; ++r) {
                    const int prow = 4 * lg + r;
                    const int swz  = (prow & 7) << 3;
                    #pragma unroll
                    for (int t = 0; t < 4; ++t)
                        Pw[prow * 64 + ((16 * t + lr) ^ swz)] = pb[t][r];
                }

                // O += P V
                bf16x8 pa[2];
                #pragma unroll
                for (int s = 0; s < 2; ++s)
                    pa[s] = *reinterpret_cast<const bf16x8*>(&Pw[lr * 64 + ((32 * s + dk0) ^ ((lr & 7) << 3))]);
                #pragma unroll
                for (int u = 0; u < 4; ++u) {
                    const int vrow = 16 * u + lr;
                    const int swz  = (vrow & 7) << 3;
                    #pragma unroll
                    for (int s = 0; s < 2; ++s) {
                        const bf16x8 vbf = *reinterpret_cast<const bf16x8*>(&Vc[vrow * 64 + ((32 * s + dk0) ^ swz)]);
                        oa[u] = __builtin_amdgcn_mfma_f32_16x16x32_bf16(pa[s], vbf, oa[u], 0, 0, 0);
                    }
                }
            }

            // stage pair p+1 into the buffer all waves finished reading at iter p-1
            if (pf) store_pair((p + 1) & 1);
            __syncthreads();  // single barrier: stores visible + reads-done ordering
        }

        // ---- merge key-split groups: reduce l, exchange (m,l,O) via LDS
        #pragma unroll
        for (int off = 8; off >= 1; off >>= 1)
            #pragma unroll
            for (int r = 0; r < 4; ++r)
                l_run[r] += __shfl_xor(l_run[r], off);

        short* Obuf = &Ps[4 + qsub][0];  // group-1 wave's own P buffer
        if (grp == 1) {
            #pragma unroll
            for (int r = 0; r < 4; ++r) {
                const int row = 4 * lg + r;
                #pragma unroll
                for (int u = 0; u < 4; ++u)
                    Obuf[row * 64 + 16 * u + lr] = f2bf(oa[u][r]);
                if (lr == 0) { Ml[qsub][row][0] = m_run[r]; Ml[qsub][row][1] = l_run[r]; }
            }
        }
        __syncthreads();
        if (grp == 0) {
            float* Ob = O + bo + (size_t)(q0 + 16 * qsub) * DK;
            #pragma unroll
            for (int r = 0; r < 4; ++r) {
                const int row = 4 * lg + r;
                const float m1 = Ml[qsub][row][0];
                const float l1 = Ml[qsub][row][1];
                const float mm = fmaxf(m_run[r], m1);
                const float a0 = (m_run[r] == NEG_INF) ? 0.f : __expf(m_run[r] - mm);
                const float a1 = (m1 == NEG_INF) ? 0.f : __expf(m1 - mm);
                const float lt = a0 * l_run[r] + a1 * l1;
                const float inv = (lt > 0.f) ? (1.0f / lt) : 0.f;
                #pragma unroll
                for (int u = 0; u < 4; ++u) {
                    const float o1 = bf2f(Obuf[row * 64 + 16 * u + lr]);
                    Ob[(size_t)row * DK + 16 * u + lr] = (a0 * oa[u][r] + a1 * o1) * inv;
                }
            }
        }
        __syncthreads();  // protect merge buffers before next q-tile
    }
}

extern "C" void kernel_launch(void* const* d_in, const int* in_sizes, int n_in,
                              void* d_out, int out_size, void* d_ws, size_t ws_size,
                              hipStream_t stream) {
    (void)in_sizes; (void)n_in; (void)d_ws; (void)ws_size; (void)out_size;
    const float* q = (const float*)d_in[0];
    const float* k = (const float*)d_in[1];
    const float* v = (const float*)d_in[2];
    float* o = (float*)d_out;
    dim3 grid(32, 8);
    dim3 block(512);
    hipLaunchKernelGGL(attn_kernel, grid, block, 0, stream, q, k, v, o);
}